// Round 9
// baseline (398.478 us; speedup 1.0000x reference)
//
#include <hip/hip_runtime.h>
#include <hip/hip_bf16.h>
#include <math.h>

typedef __hip_bfloat16 bf16;
typedef __attribute__((ext_vector_type(8))) short bf16x8;
typedef __attribute__((ext_vector_type(4))) float f32x4;

#define B_  2
#define T_  2048
#define C_  2048
#define H_  16
#define HS_ 128
#define DL_ 1024
#define M_  (B_ * T_)   // 4096 tokens
#define NT64_ 32        // 32 q-tiles of 64 rows per (b,h)

// async global->LDS, 16 B per lane. LDS dest is wave-uniform base + lane*16.
__device__ inline void lds16(const bf16* g, bf16* l) {
    __builtin_amdgcn_global_load_lds(
        (const __attribute__((address_space(1))) void*)g,
        (__attribute__((address_space(3))) void*)l, 16, 0, 0);
}

// ---------------------------------------------------------------------------
// fp32 -> bf16 cast, 8 elems/thread
// ---------------------------------------------------------------------------
__global__ __launch_bounds__(256) void cast_bf16_k(
    const float* __restrict__ in, bf16* __restrict__ out)
{
    const size_t i = ((size_t)blockIdx.x * 256 + threadIdx.x) * 8;
    const float4 a = *(const float4*)(in + i);
    const float4 b = *(const float4*)(in + i + 4);
    bf16 o[8];
    o[0] = __float2bfloat16(a.x); o[1] = __float2bfloat16(a.y);
    o[2] = __float2bfloat16(a.z); o[3] = __float2bfloat16(a.w);
    o[4] = __float2bfloat16(b.x); o[5] = __float2bfloat16(b.y);
    o[6] = __float2bfloat16(b.z); o[7] = __float2bfloat16(b.w);
    *(uint4*)(out + i) = *(const uint4*)o;
}

// ---------------------------------------------------------------------------
// Fused transpose+cast of all 5 weights: blockIdx.z selects the matrix.
// ---------------------------------------------------------------------------
__global__ __launch_bounds__(256) void transpose_cast5(
    const float* __restrict__ s0, const float* __restrict__ s1,
    const float* __restrict__ s2, const float* __restrict__ s3,
    const float* __restrict__ s4,
    bf16* __restrict__ d0, bf16* __restrict__ d1, bf16* __restrict__ d2,
    bf16* __restrict__ d3, bf16* __restrict__ d4)
{
    const float* in; bf16* out; int R, Cc;
    switch (blockIdx.z) {
        case 0: in = s0; out = d0; R = C_;  Cc = C_;  break;  // Wq (C,C)
        case 1: in = s1; out = d1; R = C_;  Cc = DL_; break;  // Wc (C,DL)
        case 2: in = s2; out = d2; R = DL_; Cc = C_;  break;  // Wk (DL,C)
        case 3: in = s3; out = d3; R = DL_; Cc = C_;  break;  // Wv (DL,C)
        default: in = s4; out = d4; R = C_; Cc = C_;  break;  // Wo (C,C)
    }
    const int bx = blockIdx.x * 32, by = blockIdx.y * 32;
    if (bx >= Cc || by >= R) return;
    __shared__ float t[32][33];
    const int tx = threadIdx.x & 31, ty = threadIdx.x >> 5;
#pragma unroll
    for (int i = 0; i < 32; i += 8)
        t[ty + i][tx] = in[(size_t)(by + ty + i) * Cc + bx + tx];
    __syncthreads();
#pragma unroll
    for (int i = 0; i < 32; i += 8)
        out[(size_t)(bx + ty + i) * R + by + tx] = __float2bfloat16(t[tx][ty + i]);
}

// ---------------------------------------------------------------------------
// Shared BK=64 MFMA GEMM core (128x128 tile, 4 waves, XOR-swizzled LDS).
// ---------------------------------------------------------------------------
#define GEMM_CORE(A_, Bt_, Kdim)                                               \
    __shared__ __align__(16) bf16 As[128 * 64];                                \
    __shared__ __align__(16) bf16 Bs[128 * 64];                                \
    const int tid  = threadIdx.x;                                              \
    const int lane = tid & 63;                                                 \
    const int wave = tid >> 6;                                                 \
    const int wm = wave >> 1, wn = wave & 1;                                   \
    const int quad = lane >> 4, l16 = lane & 15;                               \
    const int sw8 = (l16 >> 1) & 7;                                            \
    f32x4 acc[4][4];                                                           \
    _Pragma("unroll")                                                          \
    for (int i = 0; i < 4; i++)                                                \
        _Pragma("unroll")                                                      \
        for (int j = 0; j < 4; j++) acc[i][j] = (f32x4){0.f, 0.f, 0.f, 0.f};   \
    const int srow = tid >> 3;                                                 \
    const int ssl  = (((tid & 7) ^ ((srow >> 1) & 7)) * 8);                    \
    const bf16* Ap = (A_)  + (size_t)(m0 + srow) * (Kdim) + ssl;               \
    const bf16* Bp = (Bt_) + (size_t)(n0 + srow) * (Kdim) + ssl;               \
    const size_t rstr = (size_t)32 * (Kdim);                                   \
    for (int k0 = 0; k0 < (Kdim); k0 += 64) {                                  \
        if (k0) __syncthreads();                                               \
        _Pragma("unroll")                                                      \
        for (int ii = 0; ii < 4; ii++) {                                       \
            lds16(Ap + ii * rstr + k0, As + ii * 2048 + tid * 8);              \
            lds16(Bp + ii * rstr + k0, Bs + ii * 2048 + tid * 8);              \
        }                                                                      \
        __syncthreads();                                                       \
        _Pragma("unroll")                                                      \
        for (int w = 0; w < 2; w++) {                                          \
            bf16x8 af[4], bfr[4];                                              \
            _Pragma("unroll")                                                  \
            for (int mi = 0; mi < 4; mi++)                                     \
                af[mi] = *(const bf16x8*)&As[(wm * 64 + mi * 16 + l16) * 64 +  \
                                            (((w << 2) | quad) ^ sw8) * 8];    \
            _Pragma("unroll")                                                  \
            for (int ni = 0; ni < 4; ni++)                                     \
                bfr[ni] = *(const bf16x8*)&Bs[(wn * 64 + ni * 16 + l16) * 64 + \
                                              (((w << 2) | quad) ^ sw8) * 8];  \
            _Pragma("unroll")                                                  \
            for (int mi = 0; mi < 4; mi++)                                     \
                _Pragma("unroll")                                              \
                for (int ni = 0; ni < 4; ni++)                                 \
                    acc[mi][ni] = __builtin_amdgcn_mfma_f32_16x16x32_bf16(     \
                        af[mi], bfr[ni], acc[mi][ni], 0, 0, 0);                \
        }                                                                      \
    }

// ---------------------------------------------------------------------------
// Generic GEMM: C(M,N) = A(M,K)@Bt(N,K)^T; bf16 out, or fp32+bias (out-proj).
// ---------------------------------------------------------------------------
__global__ __launch_bounds__(256) void gemm_bt_mfma(
    const bf16* __restrict__ A, const bf16* __restrict__ Bt,
    bf16* __restrict__ Cbf, float* __restrict__ Cf32,
    const float* __restrict__ bias, int M, int N, int K)
{
    const int m0 = blockIdx.y * 128, n0 = blockIdx.x * 128;
    GEMM_CORE(A, Bt, K)
#pragma unroll
    for (int mi = 0; mi < 4; mi++) {
#pragma unroll
        for (int ni = 0; ni < 4; ni++) {
            const int col = n0 + wn * 64 + ni * 16 + l16;
#pragma unroll
            for (int r = 0; r < 4; r++) {
                const int row = m0 + wm * 64 + mi * 16 + quad * 4 + r;
                if (Cf32)
                    Cf32[(size_t)row * N + col] = acc[mi][ni][r] + bias[col];
                else
                    Cbf[(size_t)row * N + col] = __float2bfloat16(acc[mi][ni][r]);
            }
        }
    }
}

// ---------------------------------------------------------------------------
// Fused Q+C projection: [q | clat] = x @ [Wq | Wc], N=3072.
// col<2048 -> q scaled by log2(e)/sqrt(HS) (softmax uses exp2), else -> clat.
// ---------------------------------------------------------------------------
__global__ __launch_bounds__(256) void gemm_qc_fused(
    const bf16* __restrict__ A, const bf16* __restrict__ Bt,
    bf16* __restrict__ Cq, bf16* __restrict__ Cc, int M, int K)
{
    const int m0 = blockIdx.y * 128, n0 = blockIdx.x * 128;
    GEMM_CORE(A, Bt, K)
    const bool is_q = (n0 < C_);
    const float scl = is_q ? 0.12751744f : 1.0f;   // log2(e)/sqrt(128)
    bf16* dst = is_q ? Cq : Cc;
    const int ld   = is_q ? C_ : DL_;
    const int coff = is_q ? 0 : C_;
#pragma unroll
    for (int mi = 0; mi < 4; mi++) {
#pragma unroll
        for (int ni = 0; ni < 4; ni++) {
            const int col = n0 - coff + wn * 64 + ni * 16 + l16;
#pragma unroll
            for (int r = 0; r < 4; r++) {
                const int row = m0 + wm * 64 + mi * 16 + quad * 4 + r;
                dst[(size_t)row * ld + col] = __float2bfloat16(acc[mi][ni][r] * scl);
            }
        }
    }
}

// ---------------------------------------------------------------------------
// Fused K-proj + Vt-proj (both K=1024, both consume clat): 1024 blocks.
// ---------------------------------------------------------------------------
__global__ __launch_bounds__(256) void gemm_kv_fused(
    const bf16* __restrict__ clat, const bf16* __restrict__ Wk_t,
    const bf16* __restrict__ Wv_t, bf16* __restrict__ kk, bf16* __restrict__ vt)
{
    const int bid = blockIdx.x;
    const bf16 *A, *Bt; bf16* dst; int N, m0, n0;
    if (bid < 512) { A = clat; Bt = Wk_t; dst = kk; N = C_;
                     m0 = (bid >> 4) * 128; n0 = (bid & 15) * 128; }
    else           { const int t = bid - 512;
                     A = Wv_t; Bt = clat; dst = vt; N = M_;
                     m0 = (t >> 5) * 128; n0 = (t & 31) * 128; }
    GEMM_CORE(A, Bt, DL_)
#pragma unroll
    for (int mi = 0; mi < 4; mi++) {
#pragma unroll
        for (int ni = 0; ni < 4; ni++) {
            const int col = n0 + wn * 64 + ni * 16 + l16;
#pragma unroll
            for (int r = 0; r < 4; r++) {
                const int row = m0 + wm * 64 + mi * 16 + quad * 4 + r;
                dst[(size_t)row * N + col] = __float2bfloat16(acc[mi][ni][r]);
            }
        }
    }
}

// ---------------------------------------------------------------------------
// Flash attention, dual-tile MERGED version. 256 threads = 4 waves, 2 blk/CU.
// Block -> (b,h,pa) XCD-swizzled; q-tiles A=pa, B=31-pa (64 rows each, wave
// owns 16 rows of both). Key change vs r8: kf/vf fragments are loaded from
// LDS ONCE per iter and feed MFMAs of BOTH tiles (halves ds_read when both
// active). One Ps buffer per wave reused B-then-A (same-wave lgkmcnt order).
// Softmax is exp2 (log2e folded into q prescale). kv-tiles of 64 double-
// buffered via global_load_lds + raw s_barrier + manual vmcnt.
// ---------------------------------------------------------------------------
__global__ __launch_bounds__(256) void flash_dual(
    const bf16* __restrict__ Q, const bf16* __restrict__ K,
    const bf16* __restrict__ Vt, bf16* __restrict__ Y)
{
    __shared__ __align__(16) bf16 Ks[2][4][64][32];    // 32 KB (dbuf)
    __shared__ __align__(16) bf16 Vs[2][2][128][32];   // 32 KB (dbuf)
    __shared__ __align__(16) bf16 Ps[4][16][72];       // 9 KB (+8 pad)
    const int tid  = threadIdx.x;
    const int lane = tid & 63, wv = tid >> 6;          // wv 0..3
    const int quad = lane >> 4, l16 = lane & 15;
    const int sw = (l16 >> 1) & 3;
    const int bid = blockIdx.x;
    const int bh = (bid & 7) * 4 + ((bid >> 3) & 3);   // XCD-local (b,h)
    const int pa = bid >> 5;                           // 0..15
    const int b = bh >> 4, h = bh & 15;
    const int qA0 = pa * 64, qB0 = (NT64_ - 1 - pa) * 64;
    const int jA = pa + 1;
    const int jB = NT64_ - pa;                         // jA + jB = 33

    // staging: 256 threads cover 32 KB -> 8 lds16 each
    const int sr  = tid >> 2;                          // row 0..63
    const int ssl = ((tid & 3) ^ ((sr >> 1) & 3)) * 8; // swizzled 16B slot

    // Q fragments: wave rows q0 + wv*16 + l16, 4 k-chunks, both tiles
    bf16x8 qfA[4], qfB[4];
    {
        const size_t rA = (size_t)(b * T_ + qA0 + wv * 16 + l16) * C_ + h * HS_;
        const size_t rB = (size_t)(b * T_ + qB0 + wv * 16 + l16) * C_ + h * HS_;
#pragma unroll
        for (int c = 0; c < 4; c++) {
            qfA[c] = *(const bf16x8*)(Q + rA + c * 32 + quad * 8);
            qfB[c] = *(const bf16x8*)(Q + rB + c * 32 + quad * 8);
        }
    }

    f32x4 oA[8], oB[8];
#pragma unroll
    for (int dt = 0; dt < 8; dt++) {
        oA[dt] = (f32x4){0.f, 0.f, 0.f, 0.f};
        oB[dt] = (f32x4){0.f, 0.f, 0.f, 0.f};
    }
    float lA[4] = {0.f, 0.f, 0.f, 0.f}, lB[4] = {0.f, 0.f, 0.f, 0.f};

    auto stage = [&](int j, int buf) {
        const int kv0 = j * 64;
#pragma unroll
        for (int kc = 0; kc < 4; kc++)
            lds16(K + (size_t)(b * T_ + kv0 + sr) * C_ + h * HS_ + kc * 32 + ssl,
                  &Ks[buf][kc][0][0] + tid * 8);
#pragma unroll
        for (int vc = 0; vc < 2; vc++)
#pragma unroll
            for (int hf = 0; hf < 2; hf++)
                lds16(Vt + (size_t)(h * HS_ + hf * 64 + sr) * M_ + b * T_ + kv0 + vc * 32 + ssl,
                      &Vs[buf][vc][hf * 64][0] + tid * 8);
    };

    // softmax (exp2; scale pre-folded into q) + P-write + A-frag read, one tile
    auto softmax_p = [&](f32x4* sacc, int kv0, int rowbase, float* l_s,
                         bf16x8& pa0, bf16x8& pa1) {
        float p[4][4];
        if (kv0 + 63 > rowbase) {                     // diagonal band: causal mask
#pragma unroll
            for (int nt = 0; nt < 4; nt++)
#pragma unroll
                for (int r = 0; r < 4; r++) {
                    const int col = kv0 + nt * 16 + l16;
                    const int row = rowbase + quad * 4 + r;
                    p[nt][r] = (col <= row) ? exp2f(sacc[nt][r]) : 0.f;
                }
        } else {
#pragma unroll
            for (int nt = 0; nt < 4; nt++)
#pragma unroll
                for (int r = 0; r < 4; r++)
                    p[nt][r] = exp2f(sacc[nt][r]);
        }
#pragma unroll
        for (int r = 0; r < 4; r++)
            l_s[r] += p[0][r] + p[1][r] + p[2][r] + p[3][r];
#pragma unroll
        for (int nt = 0; nt < 4; nt++)
#pragma unroll
            for (int r = 0; r < 4; r++)
                Ps[wv][quad * 4 + r][nt * 16 + l16] = __float2bfloat16(p[nt][r]);
        pa0 = *(const bf16x8*)&Ps[wv][l16][quad * 8];
        pa1 = *(const bf16x8*)&Ps[wv][l16][32 + quad * 8];
    };

    stage(0, 0);
    for (int j = 0; j < jB; j++) {
        const int kv0 = j * 64;
        if (j + 1 < jB) {
            stage(j + 1, (j + 1) & 1);
            __asm__ __volatile__("s_waitcnt vmcnt(8)" ::: "memory");   // stage j done
        } else {
            __asm__ __volatile__("s_waitcnt vmcnt(0)" ::: "memory");
        }
        __builtin_amdgcn_s_barrier();                 // stage j visible to all
        const int buf = j & 1;
        const int rbA = qA0 + wv * 16, rbB = qB0 + wv * 16;
        const bool aA = (j < jA) && (kv0 <= rbA + 15);

        // ---- S for both tiles, kf loaded once
        f32x4 sB[4], sA[4];
#pragma unroll
        for (int nt = 0; nt < 4; nt++) {
            sB[nt] = (f32x4){0.f, 0.f, 0.f, 0.f};
            sA[nt] = (f32x4){0.f, 0.f, 0.f, 0.f};
        }
#pragma unroll
        for (int c = 0; c < 4; c++) {
            bf16x8 kf[4];
#pragma unroll
            for (int nt = 0; nt < 4; nt++)
                kf[nt] = *(const bf16x8*)&Ks[buf][c][nt * 16 + l16][(quad ^ sw) * 8];
#pragma unroll
            for (int nt = 0; nt < 4; nt++)
                sB[nt] = __builtin_amdgcn_mfma_f32_16x16x32_bf16(qfB[c], kf[nt], sB[nt], 0, 0, 0);
            if (aA)
#pragma unroll
                for (int nt = 0; nt < 4; nt++)
                    sA[nt] = __builtin_amdgcn_mfma_f32_16x16x32_bf16(qfA[c], kf[nt], sA[nt], 0, 0, 0);
        }
        // ---- softmax + P (B first, then A reusing the same Ps buffer)
        bf16x8 pB0, pB1, pA0, pA1;
        softmax_p(sB, kv0, rbB, lB, pB0, pB1);
        if (aA) softmax_p(sA, kv0, rbA, lA, pA0, pA1);
        // ---- PV for both tiles, vf loaded once
#pragma unroll
        for (int dt = 0; dt < 8; dt++) {
            const bf16x8 vf0 = *(const bf16x8*)&Vs[buf][0][dt * 16 + l16][(quad ^ sw) * 8];
            const bf16x8 vf1 = *(const bf16x8*)&Vs[buf][1][dt * 16 + l16][(quad ^ sw) * 8];
            oB[dt] = __builtin_amdgcn_mfma_f32_16x16x32_bf16(pB0, vf0, oB[dt], 0, 0, 0);
            oB[dt] = __builtin_amdgcn_mfma_f32_16x16x32_bf16(pB1, vf1, oB[dt], 0, 0, 0);
            if (aA) {
                oA[dt] = __builtin_amdgcn_mfma_f32_16x16x32_bf16(pA0, vf0, oA[dt], 0, 0, 0);
                oA[dt] = __builtin_amdgcn_mfma_f32_16x16x32_bf16(pA1, vf1, oA[dt], 0, 0, 0);
            }
        }
        __asm__ __volatile__("s_waitcnt lgkmcnt(0)" ::: "memory");
        __builtin_amdgcn_s_barrier();                 // buf free for stage j+2
    }

    // ---- epilogue: reduce l across 16-lane col group, normalize, store
    auto finish = [&](int q0, f32x4* oacc, float* l_s) {
        float inv[4];
#pragma unroll
        for (int r = 0; r < 4; r++) {
            float l = l_s[r];
            l += __shfl_xor(l, 1);
            l += __shfl_xor(l, 2);
            l += __shfl_xor(l, 4);
            l += __shfl_xor(l, 8);
            inv[r] = 1.f / l;
        }
        const int rowbase = q0 + wv * 16;
#pragma unroll
        for (int dt = 0; dt < 8; dt++)
#pragma unroll
            for (int r = 0; r < 4; r++)
                Y[(size_t)(b * T_ + rowbase + quad * 4 + r) * C_ + h * HS_ + dt * 16 + l16] =
                    __float2bfloat16(oacc[dt][r] * inv[r]);
    };
    finish(qA0, oA, lA);
    finish(qB0, oB, lB);
}

// ---------------------------------------------------------------------------
extern "C" void kernel_launch(void* const* d_in, const int* in_sizes, int n_in,
                              void* d_out, int out_size, void* d_ws, size_t ws_size,
                              hipStream_t stream) {
    const float* x  = (const float*)d_in[0];
    const float* Wq = (const float*)d_in[1];
    const float* Wc = (const float*)d_in[2];
    const float* Wk = (const float*)d_in[3];
    const float* Wv = (const float*)d_in[4];
    const float* Wo = (const float*)d_in[5];
    const float* bo = (const float*)d_in[6];
    float* out = (float*)d_out;

    bf16* ws   = (bf16*)d_ws;
    bf16* x_bf = ws;                            // (M,C)
    bf16* Wq_t = x_bf + (size_t)M_ * C_;        // (C,C)   contiguous with Wc_t
    bf16* Wc_t = Wq_t + (size_t)C_ * C_;        // (DL,C)
    bf16* Wk_t = Wc_t + (size_t)DL_ * C_;       // (C,DL)
    bf16* Wv_t = Wk_t + (size_t)C_ * DL_;       // (C,DL)
    bf16* Wo_t = Wv_t + (size_t)C_ * DL_;       // (C,C)
    bf16* q    = Wo_t + (size_t)C_ * C_;        // (M,C)  pre-scaled by log2e/sqrt(HS)
    bf16* clat = q    + (size_t)M_ * C_;        // (M,DL)
    bf16* kk   = clat + (size_t)M_ * DL_;       // (M,C)
    bf16* vt   = kk   + (size_t)M_ * C_;        // (C,M)  V transposed
    bf16* y    = vt   + (size_t)C_ * M_;        // (M,C)

    const dim3 blk(256);

    cast_bf16_k<<<dim3((M_ * C_) / (256 * 8)), blk, 0, stream>>>(x, x_bf);
    transpose_cast5<<<dim3(C_ / 32, C_ / 32, 5), blk, 0, stream>>>(
        Wq, Wc, Wk, Wv, Wo, Wq_t, Wc_t, Wk_t, Wv_t, Wo_t);

    // fused [q | clat] projection: Bt = [Wq_t ; Wc_t] (3072 x 2048)
    gemm_qc_fused<<<dim3((C_ + DL_) / 128, M_ / 128), blk, 0, stream>>>(
        x_bf, Wq_t, q, clat, M_, C_);
    // fused K-proj + Vt-proj (1024 blocks, both K=1024)
    gemm_kv_fused<<<dim3(1024), blk, 0, stream>>>(clat, Wk_t, Wv_t, kk, vt);

    flash_dual<<<dim3((NT64_ / 2) * H_ * B_), blk, 0, stream>>>(q, kk, vt, y);

    gemm_bt_mfma<<<dim3(C_ / 128, M_ / 128), blk, 0, stream>>>(
        y, Wo_t, nullptr, out, bo, M_, C_, C_);
}